// Round 4
// baseline (185.035 us; speedup 1.0000x reference)
//
#include <hip/hip_runtime.h>
#include <float.h>
#include <stdint.h>

#define HH 128
#define NROWS 32768
#define KCODES 4096
#define BM 64
#define BN 64
#define NTILES (KCODES / BN)

typedef _Float16 half8 __attribute__((ext_vector_type(8)));
typedef _Float16 half4_t __attribute__((ext_vector_type(4)));
typedef float floatx4 __attribute__((ext_vector_type(4)));
typedef float floatx16 __attribute__((ext_vector_type(16)));

// ---------------------------------------------------------------------------
// Fast path: w pre-split into hi/lo fp16 stored in B-fragment order so the
// main kernel loads fragments with plain global_load_dwordx4 (no LDS at all
// in the k-loop, no __syncthreads -> compiler emits fine-grained vmcnt(N)).
//
// Fragment-plane layout (2 MB in d_ws at byte offset 16384):
//   chunk index ci = (tile*8 + s)*2 + cg          (tile 0..63, s 0..7, cg 0..1)
//   chunk = 2 KB: hi half8[64] then lo half8[64], entry index = lane = kh*32+c32
//   holds w[code = tile*64 + cg*32 + c32][h = s*16 + kh*8 .. +8]
// ---------------------------------------------------------------------------

__global__ __launch_bounds__(256) void vq_prep_frag(const float* __restrict__ w,
                                                    float* __restrict__ wsq,
                                                    ushort* __restrict__ wfrag,
                                                    float* __restrict__ loss_slot) {
    const int tid = blockIdx.x * 256 + threadIdx.x;    // 65536 = 4096 codes x 16 hgrps
    if (tid == 0) loss_slot[0] = 0.0f;                 // d_out poisoned 0xAA each launch
    const int c  = tid >> 4;                           // code
    const int hg = tid & 15;                           // h/8 group
    const int tI = c >> 6, cg = (c >> 5) & 1, c32 = c & 31;
    const int s  = hg >> 1, kh = hg & 1;

    const float4* src = reinterpret_cast<const float4*>(w + (size_t)c * HH + (hg << 3));
    float4 a = src[0], b = src[1];

    _Float16 h0 = (_Float16)a.x, h1 = (_Float16)a.y, h2 = (_Float16)a.z, h3 = (_Float16)a.w;
    _Float16 h4 = (_Float16)b.x, h5 = (_Float16)b.y, h6 = (_Float16)b.z, h7 = (_Float16)b.w;
    half8 hi = {h0, h1, h2, h3, h4, h5, h6, h7};
    half8 lo = {(_Float16)(a.x - (float)h0), (_Float16)(a.y - (float)h1),
                (_Float16)(a.z - (float)h2), (_Float16)(a.w - (float)h3),
                (_Float16)(b.x - (float)h4), (_Float16)(b.y - (float)h5),
                (_Float16)(b.z - (float)h6), (_Float16)(b.w - (float)h7)};

    const size_t ci = (size_t)((tI << 3) + s) * 2 + cg;      // chunk index
    ushort* dst = wfrag + (ci << 10);                        // 1024 ushorts / chunk
    const int e = ((kh << 5) + c32) << 3;                    // entry offset (ushorts)
    *reinterpret_cast<half8*>(dst + e)       = hi;
    *reinterpret_cast<half8*>(dst + 512 + e) = lo;

    // ||w||^2 partial: reduce over the 16 threads sharing code c (lane-aligned)
    float ssq = 0.0f;
    ssq = fmaf(a.x, a.x, ssq); ssq = fmaf(a.y, a.y, ssq);
    ssq = fmaf(a.z, a.z, ssq); ssq = fmaf(a.w, a.w, ssq);
    ssq = fmaf(b.x, b.x, ssq); ssq = fmaf(b.y, b.y, ssq);
    ssq = fmaf(b.z, b.z, ssq); ssq = fmaf(b.w, b.w, ssq);
    ssq += __shfl_xor(ssq, 1, 64);
    ssq += __shfl_xor(ssq, 2, 64);
    ssq += __shfl_xor(ssq, 4, 64);
    ssq += __shfl_xor(ssq, 8, 64);
    if (hg == 0) wsq[c] = ssq;
}

__global__ __launch_bounds__(256, 2) void vq_main_fast(
        const float* __restrict__ z, const float* __restrict__ w,
        const float* __restrict__ wsq, const ushort* __restrict__ wfrag,
        float* __restrict__ out_zq, float* __restrict__ out_idx,
        float* __restrict__ out_loss) {
    __shared__ float epmin[128];
    __shared__ int   epidx[128];
    __shared__ int   fbidx[64];
    __shared__ float lred[4];

    const int t = threadIdx.x;
    const int lane = t & 63, wid = t >> 6;
    const int col32 = lane & 31, kh = lane >> 5;
    const int wrow = (wid >> 1) << 5;      // 0 / 32 : row-tile
    const int cg   = wid & 1;              // 0 / 1  : 32-code column group
    const int rowBase = blockIdx.x * BM;

    // ---- z A-fragments straight from global into registers (hi/lo split) ----
    // A layout (32x32x16): row = lane&31, k = (lane>>5)*8 + j
    half8 zh[8], zl[8];
    {
        const float* zr = z + (size_t)(rowBase + wrow + col32) * HH + (kh << 3);
#pragma unroll
        for (int s = 0; s < 8; ++s) {
            float4 a = *reinterpret_cast<const float4*>(zr + (s << 4));
            float4 b = *reinterpret_cast<const float4*>(zr + (s << 4) + 4);
            _Float16 h0 = (_Float16)a.x, h1 = (_Float16)a.y,
                     h2 = (_Float16)a.z, h3 = (_Float16)a.w;
            _Float16 h4 = (_Float16)b.x, h5 = (_Float16)b.y,
                     h6 = (_Float16)b.z, h7 = (_Float16)b.w;
            zh[s] = (half8){h0, h1, h2, h3, h4, h5, h6, h7};
            zl[s] = (half8){(_Float16)(a.x - (float)h0), (_Float16)(a.y - (float)h1),
                            (_Float16)(a.z - (float)h2), (_Float16)(a.w - (float)h3),
                            (_Float16)(b.x - (float)h4), (_Float16)(b.y - (float)h5),
                            (_Float16)(b.z - (float)h6), (_Float16)(b.w - (float)h7)};
        }
    }

    const half8* wf = reinterpret_cast<const half8*>(wfrag);
    auto ldw = [&](int k, int s, half8& h, half8& l) {
        const int ci = (((k << 3) + s) << 1) + cg;
        const half8* p = wf + ((size_t)ci << 7) + lane;
        h = p[0];        // hi plane
        l = p[64];       // lo plane
    };

    // depth-4 rotating register prefetch (~400 cyc ahead of use > L2 latency)
    half8 whb[4], wlb[4];
#pragma unroll
    for (int p = 0; p < 4; ++p) ldw(0, p, whb[p], wlb[p]);

    float best[16];
    int   bidx[16];
#pragma unroll
    for (int r = 0; r < 16; ++r) { best[r] = FLT_MAX; bidx[r] = 0; }

    float wq = wsq[(cg << 5) + col32];
    for (int k = 0; k < NTILES; ++k) {
        const float wqn = wsq[(((k + 1) & 63) << 6) + (cg << 5) + col32];
        floatx16 acc;
#pragma unroll
        for (int r = 0; r < 16; ++r) acc[r] = 0.0f;
#pragma unroll
        for (int s = 0; s < 8; ++s) {
            half8 wh = whb[s & 3], wl = wlb[s & 3];
            const int kk = (s < 4) ? k : ((k + 1) & 63);   // wrap: tail loads unused
            ldw(kk, (s + 4) & 7, whb[s & 3], wlb[s & 3]);
            // dot = zh*wh + zl*wh + zh*wl (zl*wl ~2^-22, dropped)
            acc = __builtin_amdgcn_mfma_f32_32x32x16_f16(zh[s], wh, acc, 0, 0, 0);
            acc = __builtin_amdgcn_mfma_f32_32x32x16_f16(zl[s], wh, acc, 0, 0, 0);
            acc = __builtin_amdgcn_mfma_f32_32x32x16_f16(zh[s], wl, acc, 0, 0, 0);
        }
        const int code = (k << 6) + (cg << 5) + col32;
#pragma unroll
        for (int r = 0; r < 16; ++r) {
            float sc = fmaf(-2.0f, acc[r], wq);
            if (sc < best[r]) { best[r] = sc; bidx[r] = code; }  // strict < = first-min
        }
        wq = wqn;
    }

    // ---- min over the 32 cols (lane&31) within each lane half ----
#pragma unroll
    for (int off = 1; off < 32; off <<= 1) {
#pragma unroll
        for (int r = 0; r < 16; ++r) {
            float os = __shfl_xor(best[r], off, 64);
            int   oi = __shfl_xor(bidx[r], off, 64);
            if (os < best[r] || (os == best[r] && oi < bidx[r])) {
                best[r] = os; bidx[r] = oi;
            }
        }
    }

    if (col32 == 0) {    // lanes 0 and 32 hold their row-set minima
#pragma unroll
        for (int r = 0; r < 16; ++r) {
            // C/D layout: row = (reg&3) + 8*(reg>>2) + 4*(lane>>5)  [m74/m101]
            int row = wrow + (r & 3) + ((r >> 2) << 3) + (kh << 2);
            epmin[cg * 64 + row] = best[r];
            epidx[cg * 64 + row] = bidx[r];
        }
    }
    __syncthreads();

    if (t < BM) {
        float s0 = epmin[t], s1 = epmin[64 + t];
        int   i0 = epidx[t], i1 = epidx[64 + t];
        int   fi = (s1 < s0 || (s1 == s0 && i1 < i0)) ? i1 : i0;
        fbidx[t] = fi;
        out_idx[rowBase + t] = (float)fi;
    }
    __syncthreads();

    // ---- gather zq, write out, loss (z re-read from global, exact fp32) ----
    const float4* z4 = reinterpret_cast<const float4*>(z);
    float lsum = 0.0f;
#pragma unroll
    for (int i = 0; i < 8; ++i) {
        int g = i * 256 + t;
        int r = g >> 5, f4 = g & 31;
        int code = fbidx[r];
        float4 wv = *reinterpret_cast<const float4*>(w + (size_t)code * HH + (f4 << 2));
        float4 zv = z4[(size_t)(rowBase + r) * 32 + f4];
        float dx = wv.x - zv.x, dy = wv.y - zv.y, dz = wv.z - zv.z, dw = wv.w - zv.w;
        lsum = fmaf(dx, dx, lsum); lsum = fmaf(dy, dy, lsum);
        lsum = fmaf(dz, dz, lsum); lsum = fmaf(dw, dw, lsum);
        *reinterpret_cast<float4*>(out_zq + (size_t)(rowBase + r) * HH + (f4 << 2)) = wv;
    }
#pragma unroll
    for (int off = 1; off < 64; off <<= 1) lsum += __shfl_xor(lsum, off, 64);
    if (lane == 0) lred[wid] = lsum;
    __syncthreads();
    if (t == 0) {
        float total = lred[0] + lred[1] + lred[2] + lred[3];
        atomicAdd(out_loss, total * (1.25f / 4194304.0f));  // (0.25+1)*mean, N*H
    }
}

// ---------------- fallback path (Round-2 kernel, proven 200 us) -------------
__device__ __forceinline__ int plane_off_fb(int r, int hu) {
    return ((hu << 6) | (r ^ (hu & 7))) << 3;
}

__global__ __launch_bounds__(256) void vq_prep_fb(const float* __restrict__ w,
                                                  float* __restrict__ wsq,
                                                  float* __restrict__ loss_slot) {
    int c = blockIdx.x * 256 + threadIdx.x;
    if (c == 0) loss_slot[0] = 0.0f;
    if (c < KCODES) {
        const float4* row = reinterpret_cast<const float4*>(w + (size_t)c * HH);
        float s = 0.0f;
#pragma unroll
        for (int i = 0; i < HH / 4; ++i) {
            float4 v = row[i];
            s = fmaf(v.x, v.x, s); s = fmaf(v.y, v.y, s);
            s = fmaf(v.z, v.z, s); s = fmaf(v.w, v.w, s);
        }
        wsq[c] = s;
    }
}

__device__ __forceinline__ void stage_tile_fb(const float4* __restrict__ src4,
                                              ushort* lds, int hi_base, int lo_base,
                                              int t) {
#pragma unroll
    for (int p = 0; p < 8; ++p) {
        int g = p * 256 + t;
        int r = g >> 5, f4 = g & 31;
        float4 v = src4[g];
        _Float16 h0 = (_Float16)v.x, h1 = (_Float16)v.y,
                 h2 = (_Float16)v.z, h3 = (_Float16)v.w;
        half4_t hv = {h0, h1, h2, h3};
        half4_t lv = {(_Float16)(v.x - (float)h0), (_Float16)(v.y - (float)h1),
                      (_Float16)(v.z - (float)h2), (_Float16)(v.w - (float)h3)};
        int off = plane_off_fb(r, f4 >> 1) + ((f4 & 1) << 2);
        *reinterpret_cast<half4_t*>(&lds[hi_base + off]) = hv;
        *reinterpret_cast<half4_t*>(&lds[lo_base + off]) = lv;
    }
}

__global__ __launch_bounds__(256, 2) void vq_main_fb(const float* __restrict__ z,
                                                     const float* __restrict__ w,
                                                     const float* __restrict__ wsq,
                                                     float* __restrict__ out_zq,
                                                     float* __restrict__ out_idx,
                                                     float* __restrict__ out_loss) {
    __shared__ __align__(16) ushort lds[32768];
    const int t = threadIdx.x, lane = t & 63, wid = t >> 6;
    const int q = lane >> 4, m15 = lane & 15;
    const int wrow = (wid >> 1) << 5, wcol = (wid & 1) << 5;
    const int rowBase = blockIdx.x * BM;

    stage_tile_fb(reinterpret_cast<const float4*>(z + (size_t)rowBase * HH), lds, 0, 8192, t);

    float best[2][4]; int bidx[2][4];
#pragma unroll
    for (int mt = 0; mt < 2; ++mt)
#pragma unroll
        for (int rg = 0; rg < 4; ++rg) { best[mt][rg] = FLT_MAX; bidx[mt][rg] = 0; }

    const int ar0 = wrow + m15, bn0 = wcol + m15;

    for (int k0 = 0; k0 < KCODES; k0 += BN) {
        __syncthreads();
        stage_tile_fb(reinterpret_cast<const float4*>(w + (size_t)k0 * HH), lds, 16384, 24576, t);
        __syncthreads();
        floatx4 acc[2][2];
#pragma unroll
        for (int mt = 0; mt < 2; ++mt)
#pragma unroll
            for (int nt = 0; nt < 2; ++nt) acc[mt][nt] = (floatx4){0.f, 0.f, 0.f, 0.f};
#pragma unroll
        for (int c = 0; c < 4; ++c) {
            const int hu = (c << 2) + q;
            half8 zh0 = *reinterpret_cast<half8*>(&lds[plane_off_fb(ar0, hu)]);
            half8 zh1 = *reinterpret_cast<half8*>(&lds[plane_off_fb(ar0 + 16, hu)]);
            half8 zl0 = *reinterpret_cast<half8*>(&lds[8192 + plane_off_fb(ar0, hu)]);
            half8 zl1 = *reinterpret_cast<half8*>(&lds[8192 + plane_off_fb(ar0 + 16, hu)]);
            half8 wh0 = *reinterpret_cast<half8*>(&lds[16384 + plane_off_fb(bn0, hu)]);
            half8 wh1 = *reinterpret_cast<half8*>(&lds[16384 + plane_off_fb(bn0 + 16, hu)]);
            half8 wl0 = *reinterpret_cast<half8*>(&lds[24576 + plane_off_fb(bn0, hu)]);
            half8 wl1 = *reinterpret_cast<half8*>(&lds[24576 + plane_off_fb(bn0 + 16, hu)]);
            acc[0][0] = __builtin_amdgcn_mfma_f32_16x16x32_f16(zh0, wh0, acc[0][0], 0, 0, 0);
            acc[0][1] = __builtin_amdgcn_mfma_f32_16x16x32_f16(zh0, wh1, acc[0][1], 0, 0, 0);
            acc[1][0] = __builtin_amdgcn_mfma_f32_16x16x32_f16(zh1, wh0, acc[1][0], 0, 0, 0);
            acc[1][1] = __builtin_amdgcn_mfma_f32_16x16x32_f16(zh1, wh1, acc[1][1], 0, 0, 0);
            acc[0][0] = __builtin_amdgcn_mfma_f32_16x16x32_f16(zh0, wl0, acc[0][0], 0, 0, 0);
            acc[0][1] = __builtin_amdgcn_mfma_f32_16x16x32_f16(zh0, wl1, acc[0][1], 0, 0, 0);
            acc[1][0] = __builtin_amdgcn_mfma_f32_16x16x32_f16(zh1, wl0, acc[1][0], 0, 0, 0);
            acc[1][1] = __builtin_amdgcn_mfma_f32_16x16x32_f16(zh1, wl1, acc[1][1], 0, 0, 0);
            acc[0][0] = __builtin_amdgcn_mfma_f32_16x16x32_f16(zl0, wh0, acc[0][0], 0, 0, 0);
            acc[0][1] = __builtin_amdgcn_mfma_f32_16x16x32_f16(zl0, wh1, acc[0][1], 0, 0, 0);
            acc[1][0] = __builtin_amdgcn_mfma_f32_16x16x32_f16(zl1, wh0, acc[1][0], 0, 0, 0);
            acc[1][1] = __builtin_amdgcn_mfma_f32_16x16x32_f16(zl1, wh1, acc[1][1], 0, 0, 0);
        }
        float wq0 = wsq[k0 + bn0], wq1 = wsq[k0 + bn0 + 16];
#pragma unroll
        for (int mt = 0; mt < 2; ++mt)
#pragma unroll
            for (int nt = 0; nt < 2; ++nt) {
                int code = k0 + wcol + (nt << 4) + m15;
                float wqv = nt ? wq1 : wq0;
#pragma unroll
                for (int rg = 0; rg < 4; ++rg) {
                    float s = fmaf(-2.0f, acc[mt][nt][rg], wqv);
                    if (s < best[mt][rg]) { best[mt][rg] = s; bidx[mt][rg] = code; }
                }
            }
    }
#pragma unroll
    for (int off = 1; off < 16; off <<= 1)
#pragma unroll
        for (int mt = 0; mt < 2; ++mt)
#pragma unroll
            for (int rg = 0; rg < 4; ++rg) {
                float os = __shfl_xor(best[mt][rg], off, 64);
                int   oi = __shfl_xor(bidx[mt][rg], off, 64);
                if (os < best[mt][rg] || (os == best[mt][rg] && oi < bidx[mt][rg])) {
                    best[mt][rg] = os; bidx[mt][rg] = oi;
                }
            }
    float* epmin = reinterpret_cast<float*>(lds);
    int*   epidx = reinterpret_cast<int*>(reinterpret_cast<char*>(lds) + 512);
    int*   fbidx = reinterpret_cast<int*>(reinterpret_cast<char*>(lds) + 1024);
    float* lred  = reinterpret_cast<float*>(reinterpret_cast<char*>(lds) + 1280);
    __syncthreads();
    if (m15 == 0) {
        int g = wid & 1;
#pragma unroll
        for (int mt = 0; mt < 2; ++mt)
#pragma unroll
            for (int rg = 0; rg < 4; ++rg) {
                int row = wrow + (mt << 4) + (q << 2) + rg;
                epmin[g * 64 + row] = best[mt][rg];
                epidx[g * 64 + row] = bidx[mt][rg];
            }
    }
    __syncthreads();
    if (t < BM) {
        float s0 = epmin[t], s1 = epmin[64 + t];
        int   i0 = epidx[t], i1 = epidx[64 + t];
        int   fi = (s1 < s0 || (s1 == s0 && i1 < i0)) ? i1 : i0;
        fbidx[t] = fi;
        out_idx[rowBase + t] = (float)fi;
    }
    __syncthreads();
    const float4* z4 = reinterpret_cast<const float4*>(z);
    float lsum = 0.0f;
#pragma unroll
    for (int i = 0; i < 8; ++i) {
        int g = i * 256 + t;
        int r = g >> 5, f4 = g & 31;
        int code = fbidx[r];
        float4 wv = *reinterpret_cast<const float4*>(w + (size_t)code * HH + (f4 << 2));
        float4 zv = z4[(size_t)(rowBase + r) * 32 + f4];
        float dx = wv.x - zv.x, dy = wv.y - zv.y, dz = wv.z - zv.z, dw = wv.w - zv.w;
        lsum = fmaf(dx, dx, lsum); lsum = fmaf(dy, dy, lsum);
        lsum = fmaf(dz, dz, lsum); lsum = fmaf(dw, dw, lsum);
        *reinterpret_cast<float4*>(out_zq + (size_t)(rowBase + r) * HH + (f4 << 2)) = wv;
    }
#pragma unroll
    for (int off = 1; off < 64; off <<= 1) lsum += __shfl_xor(lsum, off, 64);
    if (lane == 0) lred[wid] = lsum;
    __syncthreads();
    if (t == 0)
        atomicAdd(out_loss, (lred[0] + lred[1] + lred[2] + lred[3]) * (1.25f / 4194304.0f));
}

extern "C" void kernel_launch(void* const* d_in, const int* in_sizes, int n_in,
                              void* d_out, int out_size, void* d_ws, size_t ws_size,
                              hipStream_t stream) {
    (void)in_sizes; (void)n_in; (void)out_size;
    const float* z = (const float*)d_in[0];
    const float* w = (const float*)d_in[1];
    float* out      = (float*)d_out;
    float* out_zq   = out;
    float* out_idx  = out + (size_t)NROWS * HH;
    float* out_loss = out_idx + NROWS;
    float* wsq = (float*)d_ws;

    const size_t WS_NEED = 16384 + (size_t)KCODES * HH * 2 * 2;  // wsq + frag planes
    if (ws_size >= WS_NEED) {
        ushort* wfrag = (ushort*)((char*)d_ws + 16384);
        vq_prep_frag<<<(KCODES * 16) / 256, 256, 0, stream>>>(w, wsq, wfrag, out_loss);
        vq_main_fast<<<NROWS / BM, 256, 0, stream>>>(z, w, wsq, wfrag,
                                                     out_zq, out_idx, out_loss);
    } else {
        vq_prep_fb<<<KCODES / 256, 256, 0, stream>>>(w, wsq, out_loss);
        vq_main_fb<<<NROWS / BM, 256, 0, stream>>>(z, w, wsq, out_zq, out_idx, out_loss);
    }
}